// Round 4
// baseline (190.535 us; speedup 1.0000x reference)
//
#include <hip/hip_runtime.h>

// Problem constants (from reference): B=4, S=2048, V=64, D=1024, P=8, H=42, K=49152
#define BB 4
#define SS 2048
#define VV 64
#define DD 1024
#define PP 8
#define HH 42
#define KK 49152

static constexpr float F_EPS = 1e-12f;
static constexpr float SQRT_S = 45.254833995939045f;  // sqrt(2048)

// ---------------------------------------------------------------------------
// Kernel A: blocks [0,256): fused gates U-pass. Z-cancellation: a_v = U/Z and
// cos is scale-invariant, so we accumulate U[p,b,d] = sum_s exp(n[s,p])*ctx[s,d]
// in ONE pass over ctx (n is row-local). Block = (b, chunk of 32 s-rows);
// wave handles 8 rows in 4 groups of 2; acc[p][j] float4 in registers
// (~190 VGPR); cross-wave pairwise LDS reduce (64 KB); writes 32 KB partial.
// Blocks [256,768): h_all[r][h] = tanh(tables_row . w1[:,h] + b1[h]).
// ---------------------------------------------------------------------------
__global__ __launch_bounds__(256) void kA_fused(
    const float* __restrict__ ctx, const float* __restrict__ lora,
    const float* __restrict__ tables, const float* __restrict__ w1,
    const float* __restrict__ b1, float* __restrict__ part,
    float* __restrict__ h_all) {
  __shared__ float smem[16384];  // 64 KB: two 8192-float accumulator regions
  const int t = threadIdx.x;
  if (blockIdx.x < 256) {
    const int b = blockIdx.x >> 6;
    const int chunk = blockIdx.x & 63;
    const int wave = t >> 6, lane = t & 63;
    const int sel = lane & 7;
    const float4* ctx4 = (const float4*)ctx;
    const float4* lora4 = (const float4*)lora;
    float4 acc[PP][4];
    #pragma unroll
    for (int p = 0; p < PP; ++p)
      #pragma unroll
      for (int j = 0; j < 4; ++j) acc[p][j] = make_float4(0.f, 0.f, 0.f, 0.f);
    const int rbase = b * SS + chunk * 32 + wave * 8;

    auto reduce_accum = [&](float sq, float* d, float4* c) {
      #pragma unroll
      for (int m = 32; m >= 1; m >>= 1) sq += __shfl_xor(sq, m, 64);
      #pragma unroll
      for (int m = 1; m <= 4; m <<= 1) {
        #pragma unroll
        for (int p = 0; p < PP; ++p) d[p] += __shfl_xor(d[p], m, 64);
      }
      float v = d[0];
      v = (sel == 1) ? d[1] : v; v = (sel == 2) ? d[2] : v;
      v = (sel == 3) ? d[3] : v; v = (sel == 4) ? d[4] : v;
      v = (sel == 5) ? d[5] : v; v = (sel == 6) ? d[6] : v;
      v = (sel == 7) ? d[7] : v;
      v += __shfl_xor(v, 8, 64);
      v += __shfl_xor(v, 16, 64);
      v += __shfl_xor(v, 32, 64);
      // lane holds total dot for p = lane&7 (identical across lane-octs)
      float inv = 1.0f / fmaxf(sqrtf(sq), F_EPS);
      float cc = fmaxf(v * inv, 0.0f);
      float n = cc / fmaxf(SQRT_S * cc, F_EPS);
      float exl = expf(n);
      float ex[PP];
      #pragma unroll
      for (int p = 0; p < PP; ++p) ex[p] = __shfl(exl, p, 64);
      #pragma unroll
      for (int p = 0; p < PP; ++p) {
        #pragma unroll
        for (int j = 0; j < 4; ++j) {
          acc[p][j].x += ex[p] * c[j].x;
          acc[p][j].y += ex[p] * c[j].y;
          acc[p][j].z += ex[p] * c[j].z;
          acc[p][j].w += ex[p] * c[j].w;
        }
      }
    };

    for (int g = 0; g < 4; ++g) {
      const int r = rbase + g * 2;
      float4 c0[4], c1[4];
      float d0[PP], d1[PP];
      float sq0 = 0.f, sq1 = 0.f;
      #pragma unroll
      for (int p = 0; p < PP; ++p) { d0[p] = 0.f; d1[p] = 0.f; }
      #pragma unroll
      for (int j = 0; j < 4; ++j) {
        c0[j] = ctx4[(size_t)r * 256 + j * 64 + lane];
        c1[j] = ctx4[(size_t)(r + 1) * 256 + j * 64 + lane];
        sq0 += c0[j].x * c0[j].x + c0[j].y * c0[j].y + c0[j].z * c0[j].z + c0[j].w * c0[j].w;
        sq1 += c1[j].x * c1[j].x + c1[j].y * c1[j].y + c1[j].z * c1[j].z + c1[j].w * c1[j].w;
        #pragma unroll
        for (int p = 0; p < PP; ++p) {
          float4 e4 = lora4[p * 256 + j * 64 + lane];
          float4 u;
          u.x = e4.x / fmaxf(2.0f * fabsf(e4.x), F_EPS);
          u.y = e4.y / fmaxf(2.0f * fabsf(e4.y), F_EPS);
          u.z = e4.z / fmaxf(2.0f * fabsf(e4.z), F_EPS);
          u.w = e4.w / fmaxf(2.0f * fabsf(e4.w), F_EPS);
          d0[p] += c0[j].x * u.x + c0[j].y * u.y + c0[j].z * u.z + c0[j].w * u.w;
          d1[p] += c1[j].x * u.x + c1[j].y * u.y + c1[j].z * u.z + c1[j].w * u.w;
        }
      }
      reduce_accum(sq0, d0, c0);
      reduce_accum(sq1, d1, c1);
    }

    // cross-wave pairwise reduce: waves 0,1 write regions 0,1; waves 2,3 add.
    float4* reg = (float4*)(smem + (wave & 1) * 8192);
    if (wave < 2) {
      #pragma unroll
      for (int p = 0; p < PP; ++p)
        #pragma unroll
        for (int j = 0; j < 4; ++j)
          reg[p * 256 + j * 64 + lane] = acc[p][j];
    }
    __syncthreads();
    if (wave >= 2) {
      #pragma unroll
      for (int p = 0; p < PP; ++p)
        #pragma unroll
        for (int j = 0; j < 4; ++j) {
          int idx = p * 256 + j * 64 + lane;
          float4 o = reg[idx];
          o.x += acc[p][j].x; o.y += acc[p][j].y;
          o.z += acc[p][j].z; o.w += acc[p][j].w;
          reg[idx] = o;
        }
    }
    __syncthreads();
    const float4* r0 = (const float4*)smem;
    const float4* r1 = (const float4*)(smem + 8192);
    float4* part4 = (float4*)part;
    const size_t base = (size_t)((b * 64 + chunk) * PP) * 256;
    #pragma unroll
    for (int pp = 0; pp < PP; ++pp) {
      int idx = pp * 256 + t;
      float4 x0 = r0[idx], x1 = r1[idx];
      part4[base + idx] = make_float4(x0.x + x1.x, x0.y + x1.y,
                                      x0.z + x1.z, x0.w + x1.w);
    }
  } else {
    // ---------------- h_all row ----------------
    float* row_lds = smem;            // DD floats
    float* partial = smem + DD;       // 256 floats
    const int r = blockIdx.x - 256;
    ((float4*)row_lds)[t] = ((const float4*)(tables + (size_t)r * DD))[t];
    __syncthreads();
    const int h = t & 63, q = t >> 6;
    float acc = 0.0f;
    if (h < HH) {
      const int d0 = q * 256;
      #pragma unroll 8
      for (int dl = 0; dl < 256; ++dl) {
        acc += row_lds[d0 + dl] * w1[(size_t)(d0 + dl) * HH + h];
      }
    }
    partial[q * 64 + h] = acc;
    __syncthreads();
    if (t < HH) {
      float s = partial[t] + partial[64 + t] + partial[128 + t] + partial[192 + t];
      h_all[(size_t)r * HH + t] = tanhf(s + b1[t]);
    }
  }
}

// ---------------------------------------------------------------------------
// Kernel B: per (p,b): reduce 64 chunk-partials -> U, then
// cos = <e,U>/max(|e||U|, 1e-8)  (Z cancels exactly; clamp never binds).
// ---------------------------------------------------------------------------
__global__ __launch_bounds__(256) void kB_cos(
    const float* __restrict__ part, const float* __restrict__ lora,
    float* __restrict__ cos_ws) {
  const int t = threadIdx.x;
  const int p = blockIdx.x, b = blockIdx.y;
  const float4* part4 = (const float4*)part;
  float4 av = make_float4(0.f, 0.f, 0.f, 0.f);
  #pragma unroll 8
  for (int c = 0; c < 64; ++c) {
    float4 x = part4[(size_t)((b * 64 + c) * PP + p) * 256 + t];
    av.x += x.x; av.y += x.y; av.z += x.z; av.w += x.w;
  }
  float4 e = ((const float4*)lora)[p * 256 + t];
  float dt = av.x * e.x + av.y * e.y + av.z * e.z + av.w * e.w;
  float a2 = av.x * av.x + av.y * av.y + av.z * av.z + av.w * av.w;
  float e2 = e.x * e.x + e.y * e.y + e.z * e.z + e.w * e.w;
  #pragma unroll
  for (int m = 32; m >= 1; m >>= 1) {
    dt += __shfl_xor(dt, m, 64);
    a2 += __shfl_xor(a2, m, 64);
    e2 += __shfl_xor(e2, m, 64);
  }
  __shared__ float red[4][3];
  const int wave = t >> 6, lane = t & 63;
  if (lane == 0) { red[wave][0] = dt; red[wave][1] = a2; red[wave][2] = e2; }
  __syncthreads();
  if (t == 0) {
    float Dv = red[0][0] + red[1][0] + red[2][0] + red[3][0];
    float Av = red[0][1] + red[1][1] + red[2][1] + red[3][1];
    float Ev = red[0][2] + red[1][2] + red[2][2] + red[3][2];
    cos_ws[b * PP + p] = Dv / fmaxf(sqrtf(Ev) * sqrtf(Av), 1e-8f);
  }
}

// ---------------------------------------------------------------------------
// K7: out[bv,k] = hg[bv,:] @ w2[:,k] + b2[k], hg = sum_p gate[b,p]*h_all[gather]
// Block = (b, k-tile of 128). Thread computes 8 bv x 4 k from LDS tiles.
// ---------------------------------------------------------------------------
__global__ __launch_bounds__(256) void k7_out(
    const float* __restrict__ w2, const float* __restrict__ b2,
    const float* __restrict__ h_all, const float* __restrict__ cos_ws,
    const int* __restrict__ prefix, float* __restrict__ out) {
  __shared__ float gate_lds[PP];
  __shared__ float hg_lds[HH * 64];    // [h][v]
  __shared__ float w2_lds[HH * 128];   // [h][kk]
  const int t = threadIdx.x;
  const int b = blockIdx.y;
  const size_t kbase = (size_t)blockIdx.x * 128;
  for (int i = t; i < HH * 128; i += 256) {
    int h = i >> 7, kk = i & 127;
    w2_lds[i] = w2[(size_t)h * KK + kbase + kk];
  }
  if (t == 0) {
    float c[PP];
    float m = -1e30f;
    #pragma unroll
    for (int p = 0; p < PP; ++p) { c[p] = cos_ws[b * PP + p]; m = fmaxf(m, c[p]); }
    float s = 0.0f;
    #pragma unroll
    for (int p = 0; p < PP; ++p) { c[p] = expf(c[p] - m); s += c[p]; }
    float inv = 1.0f / s;
    float m2 = -1e30f;
    #pragma unroll
    for (int p = 0; p < PP; ++p) { c[p] *= inv; m2 = fmaxf(m2, c[p]); }
    float s2 = 0.0f;
    #pragma unroll
    for (int p = 0; p < PP; ++p) { c[p] = expf(c[p] - m2); s2 += c[p]; }
    float inv2 = 1.0f / s2;
    #pragma unroll
    for (int p = 0; p < PP; ++p) gate_lds[p] = c[p] * inv2;
  }
  __syncthreads();
  for (int idx = t; idx < 64 * HH; idx += 256) {
    int v = idx / HH;
    int h = idx - v * HH;
    int tokv = prefix[b * VV + v];
    float s = 0.0f;
    #pragma unroll
    for (int p = 0; p < PP; ++p)
      s += gate_lds[p] * h_all[(size_t)(p * VV + tokv) * HH + h];
    hg_lds[h * 64 + v] = s;
  }
  __syncthreads();
  const int tk = t & 31, tb = t >> 5;
  float4 acc[8];
  #pragma unroll
  for (int i = 0; i < 8; ++i) acc[i] = make_float4(0.f, 0.f, 0.f, 0.f);
  const float4* w24 = (const float4*)w2_lds;
  const float4* hg4 = (const float4*)hg_lds;
  #pragma unroll 2
  for (int h = 0; h < HH; ++h) {
    float4 wv = w24[h * 32 + tk];
    float4 g0 = hg4[h * 16 + tb * 2];
    float4 g1 = hg4[h * 16 + tb * 2 + 1];
    float gg[8] = {g0.x, g0.y, g0.z, g0.w, g1.x, g1.y, g1.z, g1.w};
    #pragma unroll
    for (int i = 0; i < 8; ++i) {
      acc[i].x += gg[i] * wv.x;
      acc[i].y += gg[i] * wv.y;
      acc[i].z += gg[i] * wv.z;
      acc[i].w += gg[i] * wv.w;
    }
  }
  float4 b2v = ((const float4*)b2)[(kbase >> 2) + tk];
  float4* out4 = (float4*)out;
  #pragma unroll
  for (int i = 0; i < 8; ++i) {
    int bv = b * 64 + tb * 8 + i;
    float4 o;
    o.x = acc[i].x + b2v.x;
    o.y = acc[i].y + b2v.y;
    o.z = acc[i].z + b2v.z;
    o.w = acc[i].w + b2v.w;
    out4[(((size_t)bv * KK + kbase) >> 2) + tk] = o;
  }
}

extern "C" void kernel_launch(void* const* d_in, const int* in_sizes, int n_in,
                              void* d_out, int out_size, void* d_ws, size_t ws_size,
                              hipStream_t stream) {
  const int* prefix = (const int*)d_in[0];
  const float* ctx = (const float*)d_in[1];
  const float* tables = (const float*)d_in[2];
  const float* lora = (const float*)d_in[3];
  const float* w1 = (const float*)d_in[4];
  const float* b1 = (const float*)d_in[5];
  const float* w2 = (const float*)d_in[6];
  const float* b2 = (const float*)d_in[7];
  float* out = (float*)d_out;
  char* ws = (char*)d_ws;
  // workspace (bytes): part 8388608 | cos 128 | h_all 86016  (~8.5 MB)
  float* part = (float*)ws;
  float* cos_ws = (float*)(ws + 8388608);
  float* h_all = (float*)(ws + 8388608 + 128);

  kA_fused<<<768, 256, 0, stream>>>(ctx, lora, tables, w1, b1, part, h_all);
  kB_cos<<<dim3(8, 4), 256, 0, stream>>>(part, lora, cos_ws);
  k7_out<<<dim3(384, 4), 256, 0, stream>>>(w2, b2, h_all, cos_ws, prefix, out);
}

// Round 5
// 157.554 us; speedup vs baseline: 1.2093x; 1.2093x over previous
//
#include <hip/hip_runtime.h>

// Problem constants (from reference): B=4, S=2048, V=64, D=1024, P=8, H=42, K=49152
#define BB 4
#define SS 2048
#define VV 64
#define DD 1024
#define PP 8
#define HH 42
#define KK 49152

static constexpr float F_EPS = 1e-12f;
// n[b,s,p] = c/max(sqrt(S)*c,eps) = 1/sqrt(S) if c>0 else 0  (eps binds only
// for c < 2.2e-14, prob ~0). So exp(n) is ALPHA=e^{1/sqrt(2048)} or 1.
static constexpr float ALPHA = 1.02234304f;

// ---------------------------------------------------------------------------
// K15 fused: blocks [0,512) do k1 (row dot signs -> weight), blocks
// [512,1024) do k5 (h_all). Block-uniform branch, both 256 threads.
//
// k1: wave handles 4 rows; u = e/max(2|e|,eps) staged in LDS (32 KB), read
// 32 b128/wave. Reduction: 3 butterfly levels on 8 dots within lane-octs,
// lane-select dot[lane&7], 3 cross-oct levels (27 swizzles/row). Output
// weight w = dot>0 ? ALPHA : 1 stored to n_ws (no norm/sqrt/exp needed).
// ---------------------------------------------------------------------------
__global__ __launch_bounds__(256) void k15_fused(
    const float* __restrict__ ctx, const float* __restrict__ lora,
    const float* __restrict__ tables, const float* __restrict__ w1,
    const float* __restrict__ b1, float* __restrict__ n_ws,
    float* __restrict__ h_all) {
  __shared__ float smem[PP * DD];  // 32 KB; k5 branch aliases first 5 KB
  const int t = threadIdx.x;
  if (blockIdx.x < 512) {
    // ---------------- k1: row dot signs ----------------
    for (int i = t; i < PP * DD; i += 256) {
      float e = lora[i];
      smem[i] = e / fmaxf(2.0f * fabsf(e), F_EPS);
    }
    __syncthreads();
    const int wave = t >> 6, lane = t & 63;
    const int rbase = blockIdx.x * 16 + wave * 4;
    const float4* ctx4 = (const float4*)ctx;
    const float4* u4 = (const float4*)smem;
    float dot[4][PP];
    #pragma unroll
    for (int i = 0; i < 4; ++i)
      #pragma unroll
      for (int p = 0; p < PP; ++p) dot[i][p] = 0.f;
    #pragma unroll
    for (int j = 0; j < 4; ++j) {
      float4 c[4];
      #pragma unroll
      for (int i = 0; i < 4; ++i)
        c[i] = ctx4[(size_t)(rbase + i) * 256 + j * 64 + lane];
      #pragma unroll
      for (int p = 0; p < PP; ++p) {
        float4 u = u4[p * 256 + j * 64 + lane];
        #pragma unroll
        for (int i = 0; i < 4; ++i)
          dot[i][p] += c[i].x * u.x + c[i].y * u.y + c[i].z * u.z + c[i].w * u.w;
      }
    }
    const int sel = lane & 7;
    #pragma unroll
    for (int i = 0; i < 4; ++i) {
      float d0 = dot[i][0], d1 = dot[i][1], d2 = dot[i][2], d3 = dot[i][3];
      float d4 = dot[i][4], d5 = dot[i][5], d6 = dot[i][6], d7 = dot[i][7];
      #pragma unroll
      for (int m = 1; m <= 4; m <<= 1) {
        d0 += __shfl_xor(d0, m, 64); d1 += __shfl_xor(d1, m, 64);
        d2 += __shfl_xor(d2, m, 64); d3 += __shfl_xor(d3, m, 64);
        d4 += __shfl_xor(d4, m, 64); d5 += __shfl_xor(d5, m, 64);
        d6 += __shfl_xor(d6, m, 64); d7 += __shfl_xor(d7, m, 64);
      }
      float v = d0;
      v = (sel == 1) ? d1 : v; v = (sel == 2) ? d2 : v;
      v = (sel == 3) ? d3 : v; v = (sel == 4) ? d4 : v;
      v = (sel == 5) ? d5 : v; v = (sel == 6) ? d6 : v;
      v = (sel == 7) ? d7 : v;
      v += __shfl_xor(v, 8, 64);
      v += __shfl_xor(v, 16, 64);
      v += __shfl_xor(v, 32, 64);
      if (lane < PP)
        n_ws[(size_t)(rbase + i) * 8 + lane] = (v > 0.0f) ? ALPHA : 1.0f;
    }
  } else {
    // ---------------- k5: h_all row ----------------
    float* row_lds = smem;            // DD floats
    float* partial = smem + DD;       // 256 floats
    const int r = blockIdx.x - 512;
    ((float4*)row_lds)[t] = ((const float4*)(tables + (size_t)r * DD))[t];
    __syncthreads();
    const int h = t & 63, q = t >> 6;
    float acc = 0.0f;
    if (h < HH) {
      const int d0 = q * 256;
      #pragma unroll 8
      for (int dl = 0; dl < 256; ++dl) {
        acc += row_lds[d0 + dl] * w1[(size_t)(d0 + dl) * HH + h];
      }
    }
    partial[q * 64 + h] = acc;
    __syncthreads();
    if (t < HH) {
      float s = partial[t] + partial[64 + t] + partial[128 + t] + partial[192 + t];
      h_all[(size_t)r * HH + t] = tanhf(s + b1[t]);
    }
  }
}

// ---------------------------------------------------------------------------
// K3: per (b, s-chunk of 64, d-half of 512): U-partials. Z cancels in cos, so
// no denominator pass: w_lds is a straight copy of the per-row weights.
// part[b][chunk][p][d]. Thread owns 2 d-cols (float2). grid (32,4,2).
// ---------------------------------------------------------------------------
__global__ __launch_bounds__(256) void k3_av(
    const float* __restrict__ ctx, const float* __restrict__ n_ws,
    float* __restrict__ part) {
  const int t = threadIdx.x;
  const int chunk = blockIdx.x;  // 0..31
  const int b = blockIdx.y;      // 0..3
  const int dz = blockIdx.z;     // 0..1 (d-half)
  __shared__ float w_lds[64 * PP];
  if (t < 128)
    ((float4*)w_lds)[t] =
        ((const float4*)(n_ws + (size_t)(b * SS + chunk * 64) * 8))[t];
  __syncthreads();
  float2 acc[PP];
  #pragma unroll
  for (int p = 0; p < PP; ++p) acc[p] = make_float2(0.f, 0.f);
  const float2* ctx2 = (const float2*)ctx;
  const float4* w4 = (const float4*)w_lds;
  #pragma unroll 4
  for (int sl = 0; sl < 64; ++sl) {
    int s = chunk * 64 + sl;
    float2 c = ctx2[(size_t)(b * SS + s) * 512 + dz * 256 + t];
    float4 wa = w4[sl * 2];
    float4 wb = w4[sl * 2 + 1];
    float w[PP] = {wa.x, wa.y, wa.z, wa.w, wb.x, wb.y, wb.z, wb.w};
    #pragma unroll
    for (int p = 0; p < PP; ++p) {
      acc[p].x += w[p] * c.x;
      acc[p].y += w[p] * c.y;
    }
  }
  float2* part2 = (float2*)part;
  #pragma unroll
  for (int p = 0; p < PP; ++p)
    part2[(size_t)((b * 32 + chunk) * PP + p) * 512 + dz * 256 + t] = acc[p];
}

// ---------------------------------------------------------------------------
// K4: per (p,b): reduce 32 partials -> U, cos = <e,U>/max(|e||U|,1e-8)
// (U is the unnormalized a_v; Z>0 cancels, clamp cannot bind at |U|~4e4)
// ---------------------------------------------------------------------------
__global__ __launch_bounds__(256) void k4_cos(
    const float* __restrict__ part, const float* __restrict__ lora,
    float* __restrict__ cos_ws) {
  const int t = threadIdx.x;
  const int p = blockIdx.x, b = blockIdx.y;
  const float4* part4 = (const float4*)part;
  float4 av = make_float4(0.f, 0.f, 0.f, 0.f);
  #pragma unroll 8
  for (int c = 0; c < 32; ++c) {
    float4 x = part4[(size_t)((b * 32 + c) * PP + p) * 256 + t];
    av.x += x.x; av.y += x.y; av.z += x.z; av.w += x.w;
  }
  float4 e = ((const float4*)lora)[p * 256 + t];
  float dt = av.x * e.x + av.y * e.y + av.z * e.z + av.w * e.w;
  float a2 = av.x * av.x + av.y * av.y + av.z * av.z + av.w * av.w;
  float e2 = e.x * e.x + e.y * e.y + e.z * e.z + e.w * e.w;
  #pragma unroll
  for (int m = 32; m >= 1; m >>= 1) {
    dt += __shfl_xor(dt, m, 64);
    a2 += __shfl_xor(a2, m, 64);
    e2 += __shfl_xor(e2, m, 64);
  }
  __shared__ float red[4][3];
  const int wave = t >> 6, lane = t & 63;
  if (lane == 0) { red[wave][0] = dt; red[wave][1] = a2; red[wave][2] = e2; }
  __syncthreads();
  if (t == 0) {
    float Dv = red[0][0] + red[1][0] + red[2][0] + red[3][0];
    float Av = red[0][1] + red[1][1] + red[2][1] + red[3][1];
    float Ev = red[0][2] + red[1][2] + red[2][2] + red[3][2];
    cos_ws[b * PP + p] = Dv / fmaxf(sqrtf(Ev) * sqrtf(Av), 1e-8f);
  }
}

// ---------------------------------------------------------------------------
// K7: out[bv,k] = hg[bv,:] @ w2[:,k] + b2[k], hg = sum_p gate[b,p]*h_all[gather]
// Block = (b, k-tile of 128). Thread computes 8 bv x 4 k from LDS tiles.
// ---------------------------------------------------------------------------
__global__ __launch_bounds__(256) void k7_out(
    const float* __restrict__ w2, const float* __restrict__ b2,
    const float* __restrict__ h_all, const float* __restrict__ cos_ws,
    const int* __restrict__ prefix, float* __restrict__ out) {
  __shared__ float gate_lds[PP];
  __shared__ float hg_lds[HH * 64];    // [h][v]
  __shared__ float w2_lds[HH * 128];   // [h][kk]
  const int t = threadIdx.x;
  const int b = blockIdx.y;
  const size_t kbase = (size_t)blockIdx.x * 128;
  for (int i = t; i < HH * 128; i += 256) {
    int h = i >> 7, kk = i & 127;
    w2_lds[i] = w2[(size_t)h * KK + kbase + kk];
  }
  if (t == 0) {
    float c[PP];
    float m = -1e30f;
    #pragma unroll
    for (int p = 0; p < PP; ++p) { c[p] = cos_ws[b * PP + p]; m = fmaxf(m, c[p]); }
    float s = 0.0f;
    #pragma unroll
    for (int p = 0; p < PP; ++p) { c[p] = expf(c[p] - m); s += c[p]; }
    float inv = 1.0f / s;
    float m2 = -1e30f;
    #pragma unroll
    for (int p = 0; p < PP; ++p) { c[p] *= inv; m2 = fmaxf(m2, c[p]); }
    float s2 = 0.0f;
    #pragma unroll
    for (int p = 0; p < PP; ++p) { c[p] = expf(c[p] - m2); s2 += c[p]; }
    float inv2 = 1.0f / s2;
    #pragma unroll
    for (int p = 0; p < PP; ++p) gate_lds[p] = c[p] * inv2;
  }
  __syncthreads();
  for (int idx = t; idx < 64 * HH; idx += 256) {
    int v = idx / HH;
    int h = idx - v * HH;
    int tokv = prefix[b * VV + v];
    float s = 0.0f;
    #pragma unroll
    for (int p = 0; p < PP; ++p)
      s += gate_lds[p] * h_all[(size_t)(p * VV + tokv) * HH + h];
    hg_lds[h * 64 + v] = s;
  }
  __syncthreads();
  const int tk = t & 31, tb = t >> 5;
  float4 acc[8];
  #pragma unroll
  for (int i = 0; i < 8; ++i) acc[i] = make_float4(0.f, 0.f, 0.f, 0.f);
  const float4* w24 = (const float4*)w2_lds;
  const float4* hg4 = (const float4*)hg_lds;
  #pragma unroll 2
  for (int h = 0; h < HH; ++h) {
    float4 wv = w24[h * 32 + tk];
    float4 g0 = hg4[h * 16 + tb * 2];
    float4 g1 = hg4[h * 16 + tb * 2 + 1];
    float gg[8] = {g0.x, g0.y, g0.z, g0.w, g1.x, g1.y, g1.z, g1.w};
    #pragma unroll
    for (int i = 0; i < 8; ++i) {
      acc[i].x += gg[i] * wv.x;
      acc[i].y += gg[i] * wv.y;
      acc[i].z += gg[i] * wv.z;
      acc[i].w += gg[i] * wv.w;
    }
  }
  float4 b2v = ((const float4*)b2)[(kbase >> 2) + tk];
  float4* out4 = (float4*)out;
  #pragma unroll
  for (int i = 0; i < 8; ++i) {
    int bv = b * 64 + tb * 8 + i;
    float4 o;
    o.x = acc[i].x + b2v.x;
    o.y = acc[i].y + b2v.y;
    o.z = acc[i].z + b2v.z;
    o.w = acc[i].w + b2v.w;
    out4[(((size_t)bv * KK + kbase) >> 2) + tk] = o;
  }
}

extern "C" void kernel_launch(void* const* d_in, const int* in_sizes, int n_in,
                              void* d_out, int out_size, void* d_ws, size_t ws_size,
                              hipStream_t stream) {
  const int* prefix = (const int*)d_in[0];
  const float* ctx = (const float*)d_in[1];
  const float* tables = (const float*)d_in[2];
  const float* lora = (const float*)d_in[3];
  const float* w1 = (const float*)d_in[4];
  const float* b1 = (const float*)d_in[5];
  const float* w2 = (const float*)d_in[6];
  const float* b2 = (const float*)d_in[7];
  float* out = (float*)d_out;
  char* ws = (char*)d_ws;
  // workspace (bytes): n_ws 262144 | part 4194304 | cos 128 | h_all 86016  (~4.5 MB)
  float* n_ws = (float*)ws;
  float* part = (float*)(ws + 262144);
  float* cos_ws = (float*)(ws + 262144 + 4194304);
  float* h_all = (float*)(ws + 262144 + 4194304 + 128);

  k15_fused<<<1024, 256, 0, stream>>>(ctx, lora, tables, w1, b1, n_ws, h_all);
  k3_av<<<dim3(32, 4, 2), 256, 0, stream>>>(ctx, n_ws, part);
  k4_cos<<<dim3(8, 4), 256, 0, stream>>>(part, lora, cos_ws);
  k7_out<<<dim3(384, 4), 256, 0, stream>>>(w2, b2, h_all, cos_ws, prefix, out);
}

// Round 6
// 152.667 us; speedup vs baseline: 1.2480x; 1.0320x over previous
//
#include <hip/hip_runtime.h>

// Problem constants (from reference): B=4, S=2048, V=64, D=1024, P=8, H=42, K=49152
#define BB 4
#define SS 2048
#define VV 64
#define DD 1024
#define PP 8
#define HH 42
#define KK 49152

static constexpr float F_EPS = 1e-12f;
// n[b,s,p] = c/max(sqrt(S)*c,eps) = 1/sqrt(S) if c>0 else 0, so the softmax
// weight (Z cancels in cos) is exp(n) = ALPHA if dot>0 else 1.
static constexpr float ALPHA = 1.02234304f;

// ---------------------------------------------------------------------------
// kU fused (512 threads): grid (192, 4).
// Blocks x<64: U-pass for (b=y, s-chunk of 32 rows):
//   phase1: u = e/max(2|e|,eps) staged in LDS (32 KB).
//   phase2: each of 8 waves computes 4 row-dots (j-loop, 8 p per lane-oct,
//           27 swizzles/row), writes w = dot>0 ? ALPHA : 1 to w_lds (1 KB).
//   phase3: thread owns float2 d-column; U-partial over the 32 rows
//           (ctx re-read is block-local L2-hot); store to part (8 MB).
// Blocks x>=64: h_all row r = (x-64)*4 + y: tanh(tables_row . w1 + b1),
//   512 threads = 8 d-octants of 128.
// ---------------------------------------------------------------------------
__global__ __launch_bounds__(512) void kU_fused(
    const float* __restrict__ ctx, const float* __restrict__ lora,
    const float* __restrict__ tables, const float* __restrict__ w1,
    const float* __restrict__ b1, float* __restrict__ part,
    float* __restrict__ h_all) {
  __shared__ float smem[PP * DD + 16 + 32 * PP];  // 33 KB
  const int t = threadIdx.x;
  const int b = blockIdx.y;
  if (blockIdx.x < 64) {
    const int chunk = blockIdx.x;
    float* u_lds = smem;
    float* w_lds = smem + PP * DD + 16;
    for (int i = t; i < PP * DD; i += 512) {
      float e = lora[i];
      u_lds[i] = e / fmaxf(2.0f * fabsf(e), F_EPS);
    }
    __syncthreads();
    const int wave = t >> 6, lane = t & 63;
    const int rbase = b * SS + chunk * 32 + wave * 4;
    const float4* ctx4 = (const float4*)ctx;
    const float4* u4 = (const float4*)u_lds;
    float dot[4][PP];
    #pragma unroll
    for (int i = 0; i < 4; ++i)
      #pragma unroll
      for (int p = 0; p < PP; ++p) dot[i][p] = 0.f;
    #pragma unroll
    for (int j = 0; j < 4; ++j) {
      float4 c[4];
      #pragma unroll
      for (int i = 0; i < 4; ++i)
        c[i] = ctx4[(size_t)(rbase + i) * 256 + j * 64 + lane];
      #pragma unroll
      for (int p = 0; p < PP; ++p) {
        float4 u = u4[p * 256 + j * 64 + lane];
        #pragma unroll
        for (int i = 0; i < 4; ++i)
          dot[i][p] += c[i].x * u.x + c[i].y * u.y + c[i].z * u.z + c[i].w * u.w;
      }
    }
    const int sel = lane & 7;
    #pragma unroll
    for (int i = 0; i < 4; ++i) {
      float d0 = dot[i][0], d1 = dot[i][1], d2 = dot[i][2], d3 = dot[i][3];
      float d4 = dot[i][4], d5 = dot[i][5], d6 = dot[i][6], d7 = dot[i][7];
      #pragma unroll
      for (int m = 1; m <= 4; m <<= 1) {
        d0 += __shfl_xor(d0, m, 64); d1 += __shfl_xor(d1, m, 64);
        d2 += __shfl_xor(d2, m, 64); d3 += __shfl_xor(d3, m, 64);
        d4 += __shfl_xor(d4, m, 64); d5 += __shfl_xor(d5, m, 64);
        d6 += __shfl_xor(d6, m, 64); d7 += __shfl_xor(d7, m, 64);
      }
      float v = d0;
      v = (sel == 1) ? d1 : v; v = (sel == 2) ? d2 : v;
      v = (sel == 3) ? d3 : v; v = (sel == 4) ? d4 : v;
      v = (sel == 5) ? d5 : v; v = (sel == 6) ? d6 : v;
      v = (sel == 7) ? d7 : v;
      v += __shfl_xor(v, 8, 64);
      v += __shfl_xor(v, 16, 64);
      v += __shfl_xor(v, 32, 64);
      if (lane < PP)
        w_lds[(wave * 4 + i) * PP + lane] = (v > 0.0f) ? ALPHA : 1.0f;
    }
    __syncthreads();
    // phase 3: weighted accumulation, thread owns d-cols {2t, 2t+1}
    float2 acc[PP];
    #pragma unroll
    for (int p = 0; p < PP; ++p) acc[p] = make_float2(0.f, 0.f);
    const float2* ctx2 = (const float2*)ctx;
    const float4* w4 = (const float4*)w_lds;
    #pragma unroll 4
    for (int sl = 0; sl < 32; ++sl) {
      float2 c = ctx2[(size_t)(b * SS + chunk * 32 + sl) * 512 + t];
      float4 wa = w4[sl * 2];
      float4 wb = w4[sl * 2 + 1];
      float w[PP] = {wa.x, wa.y, wa.z, wa.w, wb.x, wb.y, wb.z, wb.w};
      #pragma unroll
      for (int p = 0; p < PP; ++p) {
        acc[p].x += w[p] * c.x;
        acc[p].y += w[p] * c.y;
      }
    }
    float2* part2 = (float2*)part;
    #pragma unroll
    for (int p = 0; p < PP; ++p)
      part2[(size_t)((b * 64 + chunk) * PP + p) * 512 + t] = acc[p];
  } else {
    // ---------------- h_all row (512 threads, 8 octants) ----------------
    float* row_lds = smem;            // DD floats
    float* partial = smem + DD;       // 512 floats
    const int r = (blockIdx.x - 64) * 4 + b;
    ((float2*)row_lds)[t] = ((const float2*)(tables + (size_t)r * DD))[t];
    __syncthreads();
    const int h = t & 63, q = t >> 6;  // q in 0..7, 128-d octant
    float acc = 0.0f;
    if (h < HH) {
      const int d0 = q * 128;
      #pragma unroll 8
      for (int dl = 0; dl < 128; ++dl) {
        acc += row_lds[d0 + dl] * w1[(size_t)(d0 + dl) * HH + h];
      }
    }
    partial[q * 64 + h] = acc;
    __syncthreads();
    if (t < HH) {
      float s = 0.0f;
      #pragma unroll
      for (int q8 = 0; q8 < 8; ++q8) s += partial[q8 * 64 + t];
      h_all[(size_t)r * HH + t] = tanhf(s + b1[t]);
    }
  }
}

// ---------------------------------------------------------------------------
// K4: per (p,b): reduce 64 chunk-partials -> U, cos = <e,U>/max(|e||U|,1e-8)
// (U is the unnormalized a_v; Z>0 cancels, clamp cannot bind at |U|~4e4)
// ---------------------------------------------------------------------------
__global__ __launch_bounds__(256) void k4_cos(
    const float* __restrict__ part, const float* __restrict__ lora,
    float* __restrict__ cos_ws) {
  const int t = threadIdx.x;
  const int p = blockIdx.x, b = blockIdx.y;
  const float4* part4 = (const float4*)part;
  float4 av = make_float4(0.f, 0.f, 0.f, 0.f);
  #pragma unroll 8
  for (int c = 0; c < 64; ++c) {
    float4 x = part4[(size_t)((b * 64 + c) * PP + p) * 256 + t];
    av.x += x.x; av.y += x.y; av.z += x.z; av.w += x.w;
  }
  float4 e = ((const float4*)lora)[p * 256 + t];
  float dt = av.x * e.x + av.y * e.y + av.z * e.z + av.w * e.w;
  float a2 = av.x * av.x + av.y * av.y + av.z * av.z + av.w * av.w;
  float e2 = e.x * e.x + e.y * e.y + e.z * e.z + e.w * e.w;
  #pragma unroll
  for (int m = 32; m >= 1; m >>= 1) {
    dt += __shfl_xor(dt, m, 64);
    a2 += __shfl_xor(a2, m, 64);
    e2 += __shfl_xor(e2, m, 64);
  }
  __shared__ float red[4][3];
  const int wave = t >> 6, lane = t & 63;
  if (lane == 0) { red[wave][0] = dt; red[wave][1] = a2; red[wave][2] = e2; }
  __syncthreads();
  if (t == 0) {
    float Dv = red[0][0] + red[1][0] + red[2][0] + red[3][0];
    float Av = red[0][1] + red[1][1] + red[2][1] + red[3][1];
    float Ev = red[0][2] + red[1][2] + red[2][2] + red[3][2];
    cos_ws[b * PP + p] = Dv / fmaxf(sqrtf(Ev) * sqrtf(Av), 1e-8f);
  }
}

// ---------------------------------------------------------------------------
// K7: out[bv,k] = hg[bv,:] @ w2[:,k] + b2[k], hg = sum_p gate[b,p]*h_all[gather]
// Block = (b, k-tile of 128). Thread computes 8 bv x 4 k from LDS tiles.
// ---------------------------------------------------------------------------
__global__ __launch_bounds__(256) void k7_out(
    const float* __restrict__ w2, const float* __restrict__ b2,
    const float* __restrict__ h_all, const float* __restrict__ cos_ws,
    const int* __restrict__ prefix, float* __restrict__ out) {
  __shared__ float gate_lds[PP];
  __shared__ float hg_lds[HH * 64];    // [h][v]
  __shared__ float w2_lds[HH * 128];   // [h][kk]
  const int t = threadIdx.x;
  const int b = blockIdx.y;
  const size_t kbase = (size_t)blockIdx.x * 128;
  for (int i = t; i < HH * 128; i += 256) {
    int h = i >> 7, kk = i & 127;
    w2_lds[i] = w2[(size_t)h * KK + kbase + kk];
  }
  if (t == 0) {
    float c[PP];
    float m = -1e30f;
    #pragma unroll
    for (int p = 0; p < PP; ++p) { c[p] = cos_ws[b * PP + p]; m = fmaxf(m, c[p]); }
    float s = 0.0f;
    #pragma unroll
    for (int p = 0; p < PP; ++p) { c[p] = expf(c[p] - m); s += c[p]; }
    float inv = 1.0f / s;
    float m2 = -1e30f;
    #pragma unroll
    for (int p = 0; p < PP; ++p) { c[p] *= inv; m2 = fmaxf(m2, c[p]); }
    float s2 = 0.0f;
    #pragma unroll
    for (int p = 0; p < PP; ++p) { c[p] = expf(c[p] - m2); s2 += c[p]; }
    float inv2 = 1.0f / s2;
    #pragma unroll
    for (int p = 0; p < PP; ++p) gate_lds[p] = c[p] * inv2;
  }
  __syncthreads();
  for (int idx = t; idx < 64 * HH; idx += 256) {
    int v = idx / HH;
    int h = idx - v * HH;
    int tokv = prefix[b * VV + v];
    float s = 0.0f;
    #pragma unroll
    for (int p = 0; p < PP; ++p)
      s += gate_lds[p] * h_all[(size_t)(p * VV + tokv) * HH + h];
    hg_lds[h * 64 + v] = s;
  }
  __syncthreads();
  const int tk = t & 31, tb = t >> 5;
  float4 acc[8];
  #pragma unroll
  for (int i = 0; i < 8; ++i) acc[i] = make_float4(0.f, 0.f, 0.f, 0.f);
  const float4* w24 = (const float4*)w2_lds;
  const float4* hg4 = (const float4*)hg_lds;
  #pragma unroll 2
  for (int h = 0; h < HH; ++h) {
    float4 wv = w24[h * 32 + tk];
    float4 g0 = hg4[h * 16 + tb * 2];
    float4 g1 = hg4[h * 16 + tb * 2 + 1];
    float gg[8] = {g0.x, g0.y, g0.z, g0.w, g1.x, g1.y, g1.z, g1.w};
    #pragma unroll
    for (int i = 0; i < 8; ++i) {
      acc[i].x += gg[i] * wv.x;
      acc[i].y += gg[i] * wv.y;
      acc[i].z += gg[i] * wv.z;
      acc[i].w += gg[i] * wv.w;
    }
  }
  float4 b2v = ((const float4*)b2)[(kbase >> 2) + tk];
  float4* out4 = (float4*)out;
  #pragma unroll
  for (int i = 0; i < 8; ++i) {
    int bv = b * 64 + tb * 8 + i;
    float4 o;
    o.x = acc[i].x + b2v.x;
    o.y = acc[i].y + b2v.y;
    o.z = acc[i].z + b2v.z;
    o.w = acc[i].w + b2v.w;
    out4[(((size_t)bv * KK + kbase) >> 2) + tk] = o;
  }
}

extern "C" void kernel_launch(void* const* d_in, const int* in_sizes, int n_in,
                              void* d_out, int out_size, void* d_ws, size_t ws_size,
                              hipStream_t stream) {
  const int* prefix = (const int*)d_in[0];
  const float* ctx = (const float*)d_in[1];
  const float* tables = (const float*)d_in[2];
  const float* lora = (const float*)d_in[3];
  const float* w1 = (const float*)d_in[4];
  const float* b1 = (const float*)d_in[5];
  const float* w2 = (const float*)d_in[6];
  const float* b2 = (const float*)d_in[7];
  float* out = (float*)d_out;
  char* ws = (char*)d_ws;
  // workspace (bytes): part 8388608 | cos 128 | h_all 86016  (~8.5 MB)
  float* part = (float*)ws;
  float* cos_ws = (float*)(ws + 8388608);
  float* h_all = (float*)(ws + 8388608 + 128);

  kU_fused<<<dim3(192, 4), 512, 0, stream>>>(ctx, lora, tables, w1, b1, part, h_all);
  k4_cos<<<dim3(8, 4), 256, 0, stream>>>(part, lora, cos_ws);
  k7_out<<<dim3(384, 4), 256, 0, stream>>>(w2, b2, h_all, cos_ws, prefix, out);
}